// Round 13
// baseline (3327.197 us; speedup 1.0000x reference)
//
#include <hip/hip_runtime.h>

static constexpr int   BATCH = 131072;
static constexpr int   TS    = 30;
static constexpr int   DD    = 10;
static constexpr int   HH    = 20;
static constexpr float EPSV  = 1e-5f;
static constexpr float INV_B = 1.0f / (float)BATCH;

static constexpr int NBLK = 256;   // cooperative blocks (1/CU) — R11's proven shape
static constexpr int NTHR = 512;   // 1 row/thread
static constexpr int NS   = 4;     // stat slot spread (blockIdx&3)
static constexpr int NVA  = 230;   // 210 tri second-moments + 20 sums
static constexpr int NVB  = 40;    // 20 sums + 20 sumsq
static constexpr int STRA = NVA * NS;
static constexpr int STRB = NVB * NS;
static constexpr int CTRW = 16;    // one 64B-padded counter per step

__device__ __forceinline__ int tri(int k, int l) {  // k <= l
    return k * (41 - k) / 2 + (l - k);
}

template <int CTRL>
__device__ __forceinline__ float dpp_add(float v) {
    int x = __builtin_amdgcn_update_dpp(0, __float_as_int(v), CTRL, 0xF, 0xF, true);
    return v + __int_as_float(x);
}

__device__ __forceinline__ float rowsum16(float v) {
    v = dpp_add<0x111>(v);
    v = dpp_add<0x112>(v);
    v = dpp_add<0x114>(v);
    v = dpp_add<0x118>(v);
    return v;   // lane 15 of each 16 holds the total
}

__device__ __forceinline__ float aloadf(const float* p) {
    return __hip_atomic_load(p, __ATOMIC_RELAXED, __HIP_MEMORY_SCOPE_AGENT);
}

// R1's exact proven barrier.
__device__ __forceinline__ void gbar(unsigned* __restrict__ c, int tid) {
    __syncthreads();
    if (tid == 0) {
        __hip_atomic_fetch_add(c, 1u, __ATOMIC_RELEASE, __HIP_MEMORY_SCOPE_AGENT);
        while (__hip_atomic_load(c, __ATOMIC_ACQUIRE, __HIP_MEMORY_SCOPE_AGENT) < (unsigned)NBLK)
            __builtin_amdgcn_s_sleep(1);
    }
    __syncthreads();
}

// ---------------- one-time transpose x[b][t][d] -> xT[t*DD+d][b]  (R10 verbatim, 117us)
__global__ void __launch_bounds__(256)
k_tr(const float* __restrict__ x, float* __restrict__ xT)
{
    const int t = blockIdx.x / (BATCH / 256);
    const int b = (blockIdx.x % (BATCH / 256)) * 256 + threadIdx.x;
    float xv[DD];
    const float2* px = reinterpret_cast<const float2*>(x + (size_t)b * TS * DD + t * DD);
#pragma unroll
    for (int i = 0; i < 5; ++i) { float2 v = px[i]; xv[2 * i] = v.x; xv[2 * i + 1] = v.y; }
#pragma unroll
    for (int d = 0; d < DD; ++d)
        xT[((size_t)t * DD + d) * BATCH + b] = xv[d];
}

// ---------------- final transpose outT[t*DD+d][b] -> out[b][t][d]
__global__ void __launch_bounds__(256)
k_trO(const float* __restrict__ outT, float* __restrict__ out)
{
    const int b = blockIdx.x * 256 + threadIdx.x;
    for (int t = 0; t < TS; ++t) {
        float ov[DD];
#pragma unroll
        for (int d = 0; d < DD; ++d)
            ov[d] = outT[((size_t)t * DD + d) * BATCH + b];
        float2* po = reinterpret_cast<float2*>(out + (size_t)b * TS * DD + t * DD);
#pragma unroll
        for (int i = 0; i < 5; ++i) po[i] = make_float2(ov[2 * i], ov[2 * i + 1]);
    }
}

// ---------------- init: prev=0, statsA(0)  (reads xT coalesced)
__global__ void __launch_bounds__(NTHR)
k_init(const float* __restrict__ xT, float* __restrict__ prevg, float* __restrict__ redA)
{
    __shared__ float lred[32 * NVA];
    const int tid     = threadIdx.x;
    const int grp     = tid >> 4;
    const bool lane15 = (tid & 15) == 15;
    const int row     = blockIdx.x * NTHR + tid;

    float xv[DD];
#pragma unroll
    for (int d = 0; d < DD; ++d) xv[d] = xT[(size_t)d * BATCH + row];
#pragma unroll
    for (int d = 0; d < DD; ++d) prevg[(size_t)d * BATCH + row] = 0.0f;

#define H0(i) ((i) < DD ? xv[i] : 0.0f)
    {
        int v = 0;
#pragma unroll
        for (int k = 0; k < 2 * DD; ++k) {
#pragma unroll
            for (int l = k; l < 2 * DD; ++l) {
                float r = rowsum16(H0(k) * H0(l));
                if (lane15) lred[grp * NVA + v] = r;
                ++v;
            }
        }
#pragma unroll
        for (int k = 0; k < 2 * DD; ++k) {
            float r = rowsum16(H0(k));
            if (lane15) lred[grp * NVA + 210 + k] = r;
        }
    }
#undef H0
    __syncthreads();
    if (tid < NVA) {
        float acc = 0.0f;
#pragma unroll
        for (int g = 0; g < 32; ++g) acc += lred[g * NVA + tid];
        atomicAdd(redA + tid * NS + (blockIdx.x & (NS - 1)), acc);
    }
}

// ---------------- one full step (R11 verbatim; only I/O addressing changed)
template <bool LAST>
__global__ void __launch_bounds__(NTHR, 1)
k_step(const float* __restrict__ xT, float* __restrict__ prevg, float* __restrict__ outT,
       const float* __restrict__ W1, const float* __restrict__ W2,
       const float* __restrict__ W3, const float* __restrict__ b3,
       const float* __restrict__ g0, const float* __restrict__ be0,
       const float* __restrict__ g1, const float* __restrict__ be1,
       const float* __restrict__ g2, const float* __restrict__ be2,
       float* __restrict__ redA, float* __restrict__ redB,
       unsigned* __restrict__ ctr, int t)
{
    __shared__ float lred[32 * NVA];
    __shared__ float sM[230], sMu[20], sCov[400], sU[400], sP[400];
    __shared__ float sW1[400], sW2[400], sW3[200], sB3[10];
    __shared__ float sA0[20], sC0[20], sA1[20], sC1[20], sA2[20], sC2[20];

    const int tid     = threadIdx.x;
    const int grp     = tid >> 4;
    const bool lane15 = (tid & 15) == 15;
    const int slot    = blockIdx.x & (NS - 1);
    const int row     = blockIdx.x * NTHR + tid;

    // ---- hoisted per-row loads (all coalesced column reads)
    float xv[DD], pv[DD], xn[DD];
#pragma unroll
    for (int d = 0; d < DD; ++d) xv[d] = xT[((size_t)t * DD + d) * BATCH + row];
#pragma unroll
    for (int d = 0; d < DD; ++d) pv[d] = prevg[(size_t)d * BATCH + row];
    if constexpr (!LAST) {
#pragma unroll
        for (int d = 0; d < DD; ++d) xn[d] = xT[((size_t)(t + 1) * DD + d) * BATCH + row];
    }

    // ---- stage weights
    if (tid < 400) { sW1[tid] = W1[t * 400 + tid]; sW2[tid] = W2[t * 400 + tid]; }
    if (tid < 200) sW3[tid] = W3[t * 200 + tid];
    if (tid >= 500 && tid < 510) sB3[tid - 500] = b3[t * DD + (tid - 500)];

    // ---- readback statsA (written by previous kernel; relaxed agent loads)
    if (tid < NVA) {
        const float* p = redA + (size_t)t * STRA + tid * NS;
        float s = 0.0f;
#pragma unroll
        for (int i = 0; i < NS; ++i) s += aloadf(p + i);
        sM[tid] = s;
    }
    __syncthreads();

    // ---- BN0 params
    if (tid < 20) {
        float mu  = sM[210 + tid] * INV_B;
        float var = fmaf(-mu, mu, sM[tri(tid, tid)] * INV_B);
        float a   = g0[t * 20 + tid] * rsqrtf(var + EPSV);
        sA0[tid] = a;
        sC0[tid] = fmaf(-mu, a, be0[t * 20 + tid]);
        sMu[tid] = mu;
    }
    __syncthreads();

    // ---- covariance + U = W1 ∘ A0
    if (tid < 400) {
        int k = tid / 20, l = tid % 20;
        int a = k < l ? k : l, b = k < l ? l : k;
        sCov[tid] = fmaf(-sMu[k], sMu[l], sM[tri(a, b)] * INV_B);
        sU[tid]   = sW1[tid] * sA0[l];
    }
    __syncthreads();

    // ---- P[j,k] = U[j,k] * (Cov[k,:] · U[j,:])
    if (tid < 400) {
        int j = tid / 20, k = tid % 20;
        float acc = 0.0f;
#pragma unroll
        for (int l = 0; l < 20; ++l)
            acc = fmaf(sCov[k * 20 + l], sU[j * 20 + l], acc);
        sP[tid] = acc * sU[tid];
    }
    __syncthreads();

    // ---- analytic BN1 params (b1 cancels in BN)
    if (tid < 20) {
        float var1 = 0.0f, m1 = 0.0f;
#pragma unroll
        for (int k = 0; k < 20; ++k) {
            var1 += sP[tid * 20 + k];
            m1    = fmaf(sU[tid * 20 + k], sMu[k], m1);
            m1    = fmaf(sW1[tid * 20 + k], sC0[k], m1);
        }
        float a1 = g1[t * 20 + tid] * rsqrtf(var1 + EPSV);
        sA1[tid] = a1;
        sC1[tid] = fmaf(-m1, a1, be1[t * 20 + tid]);
    }
    __syncthreads();

    // ---- forward layers 1,2 (y2 stays in registers across the barrier)
    float hn[20];
#pragma unroll
    for (int k = 0; k < 10; ++k) hn[k]      = fmaf(xv[k], sA0[k],      sC0[k]);
#pragma unroll
    for (int k = 0; k < 10; ++k) hn[10 + k] = fmaf(pv[k], sA0[10 + k], sC0[10 + k]);

    float h1[20];
#pragma unroll
    for (int j = 0; j < 20; ++j) {
        float y = 0.0f;
#pragma unroll
        for (int k = 0; k < 20; ++k) y = fmaf(sW1[j * 20 + k], hn[k], y);
        h1[j] = fmaxf(fmaf(y, sA1[j], sC1[j]), 0.0f);
    }
    float y2[20];
#pragma unroll
    for (int j = 0; j < 20; ++j) {
        float y = 0.0f;
#pragma unroll
        for (int k = 0; k < 20; ++k) y = fmaf(sW2[j * 20 + k], h1[k], y);
        y2[j] = y;   // b2 cancels in BN2
    }

    // ---- statsB
#pragma unroll
    for (int j = 0; j < 20; ++j) {
        float r = rowsum16(y2[j]);
        if (lane15) lred[grp * NVB + j] = r;
    }
#pragma unroll
    for (int j = 0; j < 20; ++j) {
        float r = rowsum16(y2[j] * y2[j]);
        if (lane15) lred[grp * NVB + 20 + j] = r;
    }
    __syncthreads();
    if (tid < NVB) {
        float acc = 0.0f;
#pragma unroll
        for (int g = 0; g < 32; ++g) acc += lred[g * NVB + tid];
        atomicAdd(redB + (size_t)t * STRB + tid * NS + slot, acc);
    }

    // ================= grid barrier =================
    gbar(ctr + (size_t)t * CTRW, tid);

    // ---- BN2 params
    if (tid < NVB) {
        const float* p = redB + (size_t)t * STRB + tid * NS;
        float s = 0.0f;
#pragma unroll
        for (int i = 0; i < NS; ++i) s += aloadf(p + i);
        sM[tid] = s;
    }
    __syncthreads();
    if (tid < 20) {
        float m   = sM[tid] * INV_B;
        float var = fmaf(-m, m, sM[20 + tid] * INV_B);
        float a   = g2[t * 20 + tid] * rsqrtf(var + EPSV);
        sA2[tid] = a;
        sC2[tid] = fmaf(-m, a, be2[t * 20 + tid]);
    }
    __syncthreads();

    // ---- layer 3 + output (column-major, coalesced) + prev
    float h2[20];
#pragma unroll
    for (int j = 0; j < 20; ++j)
        h2[j] = fmaxf(fmaf(y2[j], sA2[j], sC2[j]), 0.0f);

    float ov[DD];
#pragma unroll
    for (int d = 0; d < DD; ++d) {
        float a = sB3[d];
#pragma unroll
        for (int j = 0; j < 20; ++j)
            a = fmaf(sW3[d * 20 + j], h2[j], a);
        ov[d] = a;
    }
#pragma unroll
    for (int d = 0; d < DD; ++d) {
        outT[((size_t)t * DD + d) * BATCH + row] = ov[d];
        prevg[(size_t)d * BATCH + row]           = ov[d];
    }

    // ---- statsA(t+1): kernel boundary is the sync for its consumers
    if constexpr (!LAST) {
#define H0(i) ((i) < DD ? xn[i] : ov[(i) - DD])
        {
            int v = 0;
#pragma unroll
            for (int k = 0; k < 2 * DD; ++k) {
#pragma unroll
                for (int l = k; l < 2 * DD; ++l) {
                    float r = rowsum16(H0(k) * H0(l));
                    if (lane15) lred[grp * NVA + v] = r;
                    ++v;
                }
            }
#pragma unroll
            for (int k = 0; k < 2 * DD; ++k) {
                float r = rowsum16(H0(k));
                if (lane15) lred[grp * NVA + 210 + k] = r;
            }
        }
#undef H0
        __syncthreads();
        if (tid < NVA) {
            float acc = 0.0f;
#pragma unroll
            for (int g = 0; g < 32; ++g) acc += lred[g * NVA + tid];
            atomicAdd(redA + (size_t)(t + 1) * STRA + tid * NS + slot, acc);
        }
    }
}

extern "C" void kernel_launch(void* const* d_in, const int* in_sizes, int n_in,
                              void* d_out, int out_size, void* d_ws, size_t ws_size,
                              hipStream_t stream) {
    const float* x   = (const float*)d_in[0];
    const float* g0  = (const float*)d_in[1];
    const float* be0 = (const float*)d_in[2];
    const float* W1  = (const float*)d_in[3];
    const float* b1  = (const float*)d_in[4];   (void)b1;  // cancels in BN1
    const float* g1  = (const float*)d_in[5];
    const float* be1 = (const float*)d_in[6];
    const float* W2  = (const float*)d_in[7];
    const float* b2  = (const float*)d_in[8];   (void)b2;  // cancels in BN2
    const float* g2  = (const float*)d_in[9];
    const float* be2 = (const float*)d_in[10];
    const float* W3  = (const float*)d_in[11];
    const float* b3  = (const float*)d_in[12];
    float* out = (float*)d_out;

    const size_t redA_f = (size_t)TS * STRA;    // 27600
    const size_t redB_f = (size_t)TS * STRB;    //  4800
    const size_t ctr_u  = (size_t)TS * CTRW;    //   480
    float*    redA  = (float*)d_ws;
    float*    redB  = redA + redA_f;
    unsigned* ctr   = (unsigned*)(redB + redB_f);
    float*    prevg = (float*)(ctr + ctr_u);            // [DD][BATCH]      5.2 MB
    float*    xT    = prevg + (size_t)DD * BATCH;       // [TS*DD][BATCH] 157 MB
    float*    outT  = xT + (size_t)TS * DD * BATCH;     // [TS*DD][BATCH] 157 MB

    hipMemsetAsync(d_ws, 0, (redA_f + redB_f) * 4 + ctr_u * 4, stream);

    k_tr<<<TS * (BATCH / 256), 256, 0, stream>>>(x, xT);
    k_init<<<BATCH / NTHR, NTHR, 0, stream>>>(xT, prevg, redA);

    for (int t = 0; t < TS; ++t) {
        void* args[] = { (void*)&xT, (void*)&prevg, (void*)&outT,
                         (void*)&W1, (void*)&W2, (void*)&W3, (void*)&b3,
                         (void*)&g0, (void*)&be0, (void*)&g1, (void*)&be1,
                         (void*)&g2, (void*)&be2,
                         (void*)&redA, (void*)&redB, (void*)&ctr, (void*)&t };
        if (t + 1 < TS)
            hipLaunchCooperativeKernel((const void*)k_step<false>, dim3(NBLK), dim3(NTHR),
                                       args, 0, stream);
        else
            hipLaunchCooperativeKernel((const void*)k_step<true>, dim3(NBLK), dim3(NTHR),
                                       args, 0, stream);
    }

    k_trO<<<BATCH / 256, 256, 0, stream>>>(outT, out);
}

// Round 14
// 1554.573 us; speedup vs baseline: 2.1403x; 2.1403x over previous
//
#include <hip/hip_runtime.h>

static constexpr int   BATCH = 131072;
static constexpr int   TS    = 30;
static constexpr int   DD    = 10;
static constexpr int   HH    = 20;
static constexpr float EPSV  = 1e-5f;
static constexpr float INV_B = 1.0f / (float)BATCH;

static constexpr int NTHR = 256;
static constexpr int NBLK = 256;            // halved grid; 2 rows/thread
static constexpr int RPT  = 2;
static constexpr int TT   = NBLK * NTHR;    // 65536: rows gt and gt+TT
static constexpr int NS   = 8;              // stat slot spread (blockIdx&7)
static constexpr int NVA  = 230;            // 210 tri second-moments + 20 sums
static constexpr int NVB  = 40;             // 20 sums + 20 sumsq
static constexpr int STRA = NVA * NS;
static constexpr int STRB = NVB * NS;

__device__ __forceinline__ int tri(int k, int l) {  // k <= l
    return k * (41 - k) / 2 + (l - k);
}

template <int CTRL>
__device__ __forceinline__ float dpp_add(float v) {
    int x = __builtin_amdgcn_update_dpp(0, __float_as_int(v), CTRL, 0xF, 0xF, true);
    return v + __int_as_float(x);
}

__device__ __forceinline__ float rowsum16(float v) {
    v = dpp_add<0x111>(v);
    v = dpp_add<0x112>(v);
    v = dpp_add<0x114>(v);
    v = dpp_add<0x118>(v);
    return v;   // lane 15 of each 16 holds the total
}

// ---------------- forward kernel: params(analytic BN0/BN1) + layers1,2 + y2 stats
__global__ void __launch_bounds__(NTHR)
k_fwd(const float* __restrict__ x, const float* __restrict__ prevg,
      float* __restrict__ y2g,
      const float* __restrict__ W1, const float* __restrict__ W2,
      const float* __restrict__ g0, const float* __restrict__ be0,
      const float* __restrict__ g1, const float* __restrict__ be1,
      const float* __restrict__ redA, float* __restrict__ redB, int t)
{
    __shared__ float sW1[400], sW2[400];
    __shared__ float sM[230], sMu[20], sCov[400], sU[400], sP[400];
    __shared__ float sA0[20], sC0[20], sA1[20], sC1[20];
    __shared__ float lred[16 * NVB];

    const int tid     = threadIdx.x;
    const int grp     = tid >> 4;
    const bool lane15 = (tid & 15) == 15;
    const int gt      = blockIdx.x * NTHR + tid;

    // ---- hoisted per-row loads (latency overlaps the param preamble)
    float xv[RPT][DD], pv[RPT][DD];
#pragma unroll
    for (int r = 0; r < RPT; ++r) {
        const float2* px = reinterpret_cast<const float2*>(x + (size_t)(gt + r * TT) * TS * DD + t * DD);
#pragma unroll
        for (int i = 0; i < 5; ++i) { float2 v = px[i]; xv[r][2 * i] = v.x; xv[r][2 * i + 1] = v.y; }
    }
#pragma unroll
    for (int r = 0; r < RPT; ++r)
#pragma unroll
        for (int d = 0; d < DD; ++d) pv[r][d] = prevg[(size_t)d * BATCH + gt + r * TT];

    // ---- readback statsA (plain loads; kernel boundary is the sync)
    if (tid < NVA) {
        const float* p = redA + (size_t)t * STRA + tid * NS;
        float s = 0.0f;
#pragma unroll
        for (int i = 0; i < NS; ++i) s += p[i];
        sM[tid] = s;
    }
    for (int i = tid; i < 400; i += NTHR) { sW1[i] = W1[t * 400 + i]; sW2[i] = W2[t * 400 + i]; }
    __syncthreads();

    // ---- BN0 params
    if (tid < 20) {
        float mu  = sM[210 + tid] * INV_B;
        float var = fmaf(-mu, mu, sM[tri(tid, tid)] * INV_B);
        float a   = g0[t * 20 + tid] * rsqrtf(var + EPSV);
        sA0[tid] = a;
        sC0[tid] = fmaf(-mu, a, be0[t * 20 + tid]);
        sMu[tid] = mu;
    }
    __syncthreads();

    // ---- covariance + U = W1 ∘ A0
    for (int i = tid; i < 400; i += NTHR) {
        int k = i / 20, l = i % 20;
        int a = k < l ? k : l, b = k < l ? l : k;
        sCov[i] = fmaf(-sMu[k], sMu[l], sM[tri(a, b)] * INV_B);
        sU[i]   = sW1[i] * sA0[l];
    }
    __syncthreads();

    // ---- P[j,k] = U[j,k] * (Cov[k,:] · U[j,:])
    for (int i = tid; i < 400; i += NTHR) {
        int j = i / 20, k = i % 20;
        float acc = 0.0f;
#pragma unroll
        for (int l = 0; l < 20; ++l)
            acc = fmaf(sCov[k * 20 + l], sU[j * 20 + l], acc);
        sP[i] = acc * sU[i];
    }
    __syncthreads();

    // ---- analytic BN1 params (b1 cancels in BN)
    if (tid < 20) {
        float var1 = 0.0f, m1 = 0.0f;
#pragma unroll
        for (int k = 0; k < 20; ++k) {
            var1 += sP[tid * 20 + k];
            m1    = fmaf(sU[tid * 20 + k], sMu[k], m1);
            m1    = fmaf(sW1[tid * 20 + k], sC0[k], m1);
        }
        float a1 = g1[t * 20 + tid] * rsqrtf(var1 + EPSV);
        sA1[tid] = a1;
        sC1[tid] = fmaf(-m1, a1, be1[t * 20 + tid]);
    }
    __syncthreads();

    // ---- per-row forward (both rows)
    float y2[RPT][HH];
#pragma unroll
    for (int r = 0; r < RPT; ++r) {
        float hn[20];
#pragma unroll
        for (int k = 0; k < 10; ++k) hn[k]      = fmaf(xv[r][k], sA0[k],      sC0[k]);
#pragma unroll
        for (int k = 0; k < 10; ++k) hn[10 + k] = fmaf(pv[r][k], sA0[10 + k], sC0[10 + k]);

        float h1[20];
#pragma unroll
        for (int j = 0; j < 20; ++j) {
            float y = 0.0f;
#pragma unroll
            for (int k = 0; k < 20; ++k) y = fmaf(sW1[j * 20 + k], hn[k], y);
            h1[j] = fmaxf(fmaf(y, sA1[j], sC1[j]), 0.0f);
        }
#pragma unroll
        for (int j = 0; j < 20; ++j) {
            float y = 0.0f;
#pragma unroll
            for (int k = 0; k < 20; ++k) y = fmaf(sW2[j * 20 + k], h1[k], y);
            y2[r][j] = y;   // b2 cancels in BN2
            y2g[(size_t)j * BATCH + gt + r * TT] = y;
        }
    }

    // ---- y2 stats (combine rows, then reduce)
#pragma unroll
    for (int j = 0; j < 20; ++j) {
        float r = rowsum16(y2[0][j] + y2[1][j]);
        if (lane15) lred[grp * NVB + j] = r;
    }
#pragma unroll
    for (int j = 0; j < 20; ++j) {
        float r = rowsum16(fmaf(y2[0][j], y2[0][j], y2[1][j] * y2[1][j]));
        if (lane15) lred[grp * NVB + 20 + j] = r;
    }
    __syncthreads();
    if (tid < NVB) {
        float acc = 0.0f;
#pragma unroll
        for (int g = 0; g < 16; ++g) acc += lred[g * NVB + tid];
        atomicAdd(redB + (size_t)t * STRB + tid * NS + (blockIdx.x & (NS - 1)), acc);
    }
}

// ---------------- out kernel: finish step t-1 (BN2+layer3+out+prev), begin step t (statsA)
template <bool HF, bool HB>
__global__ void __launch_bounds__(NTHR)
k_out(const float* __restrict__ x, float* __restrict__ prevg,
      const float* __restrict__ y2g, float* __restrict__ outg,
      const float* __restrict__ W3, const float* __restrict__ b3,
      const float* __restrict__ g2, const float* __restrict__ be2,
      const float* __restrict__ redB, float* __restrict__ redA, int t)
{
    __shared__ float sW3[200], sB3[10], sA2[20], sC2[20], sSB[40];
    __shared__ float lred[16 * NVA];

    const int tid     = threadIdx.x;
    const int grp     = tid >> 4;
    const bool lane15 = (tid & 15) == 15;
    const int gt      = blockIdx.x * NTHR + tid;

    // ---- hoisted per-row loads
    float xv[RPT][DD];
    if constexpr (HB) {
#pragma unroll
        for (int r = 0; r < RPT; ++r) {
            const float2* px = reinterpret_cast<const float2*>(x + (size_t)(gt + r * TT) * TS * DD + t * DD);
#pragma unroll
            for (int i = 0; i < 5; ++i) { float2 v = px[i]; xv[r][2 * i] = v.x; xv[r][2 * i + 1] = v.y; }
        }
    }
    float y2v[RPT][HH];
    if constexpr (HF) {
#pragma unroll
        for (int r = 0; r < RPT; ++r)
#pragma unroll
            for (int j = 0; j < 20; ++j) y2v[r][j] = y2g[(size_t)j * BATCH + gt + r * TT];
    }

    float pv[RPT][DD];
    if constexpr (HF) {
        const int tf = t - 1;
        if (tid < NVB) {
            const float* p = redB + (size_t)tf * STRB + tid * NS;
            float s = 0.0f;
#pragma unroll
            for (int i = 0; i < NS; ++i) s += p[i];
            sSB[tid] = s;
        }
        if (tid < 200) sW3[tid] = W3[tf * 200 + tid];
        if (tid >= 200 && tid < 210) sB3[tid - 200] = b3[tf * DD + (tid - 200)];
        __syncthreads();
        if (tid < 20) {
            float m   = sSB[tid] * INV_B;
            float var = fmaf(-m, m, sSB[20 + tid] * INV_B);
            float a   = g2[tf * 20 + tid] * rsqrtf(var + EPSV);
            sA2[tid] = a;
            sC2[tid] = fmaf(-m, a, be2[tf * 20 + tid]);
        }
        __syncthreads();

#pragma unroll
        for (int r = 0; r < RPT; ++r) {
            float h2[20];
#pragma unroll
            for (int j = 0; j < 20; ++j)
                h2[j] = fmaxf(fmaf(y2v[r][j], sA2[j], sC2[j]), 0.0f);

            float ov[DD];
#pragma unroll
            for (int d = 0; d < DD; ++d) {
                float a = sB3[d];
#pragma unroll
                for (int j = 0; j < 20; ++j)
                    a = fmaf(sW3[d * 20 + j], h2[j], a);
                ov[d] = a;
                pv[r][d] = a;
            }
            float2* po = reinterpret_cast<float2*>(outg + (size_t)(gt + r * TT) * TS * DD + tf * DD);
#pragma unroll
            for (int i = 0; i < 5; ++i) po[i] = make_float2(ov[2 * i], ov[2 * i + 1]);
#pragma unroll
            for (int d = 0; d < DD; ++d) prevg[(size_t)d * BATCH + gt + r * TT] = ov[d];
        }
    } else {
#pragma unroll
        for (int r = 0; r < RPT; ++r)
#pragma unroll
            for (int d = 0; d < DD; ++d) {
                pv[r][d] = 0.0f;
                prevg[(size_t)d * BATCH + gt + r * TT] = 0.0f;
            }
    }

    if constexpr (HB) {
#define H0A(i) ((i) < DD ? xv[0][i] : pv[0][(i) - DD])
#define H0B(i) ((i) < DD ? xv[1][i] : pv[1][(i) - DD])
        {
            int v = 0;
#pragma unroll
            for (int k = 0; k < 2 * DD; ++k) {
#pragma unroll
                for (int l = k; l < 2 * DD; ++l) {
                    float p = fmaf(H0A(k), H0A(l), H0B(k) * H0B(l));
                    float r = rowsum16(p);
                    if (lane15) lred[grp * NVA + v] = r;
                    ++v;
                }
            }
#pragma unroll
            for (int k = 0; k < 2 * DD; ++k) {
                float r = rowsum16(H0A(k) + H0B(k));
                if (lane15) lred[grp * NVA + 210 + k] = r;
            }
        }
#undef H0A
#undef H0B
        __syncthreads();
        if (tid < NVA) {
            float acc = 0.0f;
#pragma unroll
            for (int g = 0; g < 16; ++g) acc += lred[g * NVA + tid];
            atomicAdd(redA + (size_t)t * STRA + tid * NS + (blockIdx.x & (NS - 1)), acc);
        }
    }
}

extern "C" void kernel_launch(void* const* d_in, const int* in_sizes, int n_in,
                              void* d_out, int out_size, void* d_ws, size_t ws_size,
                              hipStream_t stream) {
    const float* x   = (const float*)d_in[0];
    const float* g0  = (const float*)d_in[1];
    const float* be0 = (const float*)d_in[2];
    const float* W1  = (const float*)d_in[3];
    const float* b1  = (const float*)d_in[4];   (void)b1;  // cancels in BN1
    const float* g1  = (const float*)d_in[5];
    const float* be1 = (const float*)d_in[6];
    const float* W2  = (const float*)d_in[7];
    const float* b2  = (const float*)d_in[8];   (void)b2;  // cancels in BN2
    const float* g2  = (const float*)d_in[9];
    const float* be2 = (const float*)d_in[10];
    const float* W3  = (const float*)d_in[11];
    const float* b3  = (const float*)d_in[12];
    float* out = (float*)d_out;

    const size_t redA_f = (size_t)TS * STRA;    // 55200
    const size_t redB_f = (size_t)TS * STRB;    //  9600
    float* redA  = (float*)d_ws;
    float* redB  = redA + redA_f;
    float* prevg = redB + redB_f;                     // [DD][BATCH]   5.2 MB
    float* y2g   = prevg + (size_t)DD * BATCH;        // [HH][BATCH]  10.5 MB

    // zero only the stat accumulators; prevg is fully written by k_out before use
    hipMemsetAsync(d_ws, 0, (redA_f + redB_f) * sizeof(float), stream);

    // t=0: begin only (prev := 0)
    k_out<false, true><<<NBLK, NTHR, 0, stream>>>(x, prevg, y2g, out, W3, b3, g2, be2,
                                                  redB, redA, 0);
    for (int t = 0; t < TS; ++t) {
        k_fwd<<<NBLK, NTHR, 0, stream>>>(x, prevg, y2g, W1, W2, g0, be0, g1, be1,
                                         redA, redB, t);
        if (t + 1 < TS)
            k_out<true, true><<<NBLK, NTHR, 0, stream>>>(x, prevg, y2g, out, W3, b3,
                                                         g2, be2, redB, redA, t + 1);
        else
            k_out<true, false><<<NBLK, NTHR, 0, stream>>>(x, prevg, y2g, out, W3, b3,
                                                          g2, be2, redB, redA, t + 1);
    }
}

// Round 15
// 1497.200 us; speedup vs baseline: 2.2223x; 1.0383x over previous
//
#include <hip/hip_runtime.h>

static constexpr int   BATCH = 131072;
static constexpr int   TS    = 30;
static constexpr int   DD    = 10;
static constexpr int   HH    = 20;
static constexpr float EPSV  = 1e-5f;
static constexpr float INV_B = 1.0f / (float)BATCH;

static constexpr int NBLK = 256;            // == CU count; regular launch, all co-resident
static constexpr int NTHR = 256;
static constexpr int RPT  = 2;
static constexpr int TT   = NBLK * NTHR;    // 65536: rows gt and gt+TT
static constexpr int NS   = 8;              // stat slot spread (blockIdx&7)
static constexpr int NVA  = 230;            // 210 tri second-moments + 20 sums
static constexpr int NVB  = 40;             // 20 sums + 20 sumsq
static constexpr int STRA = NVA * NS;
static constexpr int STRB = NVB * NS;
static constexpr int CTRW = 16;             // one 64B-padded counter per step

__device__ __forceinline__ int tri(int k, int l) {  // k <= l
    return k * (41 - k) / 2 + (l - k);
}

template <int CTRL>
__device__ __forceinline__ float dpp_add(float v) {
    int x = __builtin_amdgcn_update_dpp(0, __float_as_int(v), CTRL, 0xF, 0xF, true);
    return v + __int_as_float(x);
}

__device__ __forceinline__ float rowsum16(float v) {
    v = dpp_add<0x111>(v);
    v = dpp_add<0x112>(v);
    v = dpp_add<0x114>(v);
    v = dpp_add<0x118>(v);
    return v;   // lane 15 of each 16 holds the total
}

__device__ __forceinline__ float aloadf(const float* p) {
    return __hip_atomic_load(p, __ATOMIC_RELAXED, __HIP_MEMORY_SCOPE_AGENT);
}

// R1's exact proven barrier: release arrival, acquire spin, flat counter.
__device__ __forceinline__ void gbar(unsigned* __restrict__ c, int tid) {
    __syncthreads();   // drains this block's vmem (incl. stat atomics)
    if (tid == 0) {
        __hip_atomic_fetch_add(c, 1u, __ATOMIC_RELEASE, __HIP_MEMORY_SCOPE_AGENT);
        while (__hip_atomic_load(c, __ATOMIC_ACQUIRE, __HIP_MEMORY_SCOPE_AGENT) < (unsigned)NBLK)
            __builtin_amdgcn_s_sleep(1);
    }
    __syncthreads();
}

// ---------------- init: prev=0, statsA(0) ----------------
__global__ void __launch_bounds__(NTHR)
k_init(const float* __restrict__ x, float* __restrict__ prevg, float* __restrict__ redA)
{
    __shared__ float lred[16 * NVA];
    const int tid     = threadIdx.x;
    const int grp     = tid >> 4;
    const bool lane15 = (tid & 15) == 15;
    const int gt      = blockIdx.x * NTHR + tid;

    float xv[RPT][DD];
#pragma unroll
    for (int r = 0; r < RPT; ++r) {
        const float2* px = reinterpret_cast<const float2*>(x + (size_t)(gt + r * TT) * TS * DD);
#pragma unroll
        for (int i = 0; i < 5; ++i) { float2 v = px[i]; xv[r][2 * i] = v.x; xv[r][2 * i + 1] = v.y; }
    }
#pragma unroll
    for (int r = 0; r < RPT; ++r)
#pragma unroll
        for (int d = 0; d < DD; ++d) prevg[(size_t)d * BATCH + gt + r * TT] = 0.0f;

#define H0A(i) ((i) < DD ? xv[0][i] : 0.0f)
#define H0B(i) ((i) < DD ? xv[1][i] : 0.0f)
    {
        int v = 0;
#pragma unroll
        for (int k = 0; k < 2 * DD; ++k) {
#pragma unroll
            for (int l = k; l < 2 * DD; ++l) {
                float p = fmaf(H0A(k), H0A(l), H0B(k) * H0B(l));
                float r = rowsum16(p);
                if (lane15) lred[grp * NVA + v] = r;
                ++v;
            }
        }
#pragma unroll
        for (int k = 0; k < 2 * DD; ++k) {
            float r = rowsum16(H0A(k) + H0B(k));
            if (lane15) lred[grp * NVA + 210 + k] = r;
        }
    }
#undef H0A
#undef H0B
    __syncthreads();
    if (tid < NVA) {
        float acc = 0.0f;
#pragma unroll
        for (int g = 0; g < 16; ++g) acc += lred[g * NVA + tid];
        atomicAdd(redA + tid * NS + (blockIdx.x & (NS - 1)), acc);
    }
}

// ---------------- one full step, single kernel, one in-kernel grid barrier
template <bool LAST>
__global__ void __launch_bounds__(NTHR)
k_step(const float* __restrict__ x, float* __restrict__ prevg, float* __restrict__ outg,
       const float* __restrict__ W1, const float* __restrict__ W2,
       const float* __restrict__ W3, const float* __restrict__ b3,
       const float* __restrict__ g0, const float* __restrict__ be0,
       const float* __restrict__ g1, const float* __restrict__ be1,
       const float* __restrict__ g2, const float* __restrict__ be2,
       float* __restrict__ redA, float* __restrict__ redB,
       unsigned* __restrict__ ctr, int t)
{
    __shared__ float lred[16 * NVA];
    __shared__ float sM[230], sMu[20], sCov[400], sU[400], sP[400];
    __shared__ float sW1[400], sW2[400], sW3[200], sB3[10];
    __shared__ float sA0[20], sC0[20], sA1[20], sC1[20], sA2[20], sC2[20];

    const int tid     = threadIdx.x;
    const int grp     = tid >> 4;
    const bool lane15 = (tid & 15) == 15;
    const int slot    = blockIdx.x & (NS - 1);
    const int gt      = blockIdx.x * NTHR + tid;

    // ---- hoisted per-row loads (latency overlaps the param preamble)
    float xv[RPT][DD], pv[RPT][DD], xn[RPT][DD];
#pragma unroll
    for (int r = 0; r < RPT; ++r) {
        const float2* px = reinterpret_cast<const float2*>(x + (size_t)(gt + r * TT) * TS * DD + t * DD);
#pragma unroll
        for (int i = 0; i < 5; ++i) { float2 v = px[i]; xv[r][2 * i] = v.x; xv[r][2 * i + 1] = v.y; }
    }
#pragma unroll
    for (int r = 0; r < RPT; ++r)
#pragma unroll
        for (int d = 0; d < DD; ++d) pv[r][d] = prevg[(size_t)d * BATCH + gt + r * TT];
    if constexpr (!LAST) {
#pragma unroll
        for (int r = 0; r < RPT; ++r) {
            const float2* px = reinterpret_cast<const float2*>(x + (size_t)(gt + r * TT) * TS * DD + (t + 1) * DD);
#pragma unroll
            for (int i = 0; i < 5; ++i) { float2 v = px[i]; xn[r][2 * i] = v.x; xn[r][2 * i + 1] = v.y; }
        }
    }

    // ---- stage weights
    for (int i = tid; i < 400; i += NTHR) { sW1[i] = W1[t * 400 + i]; sW2[i] = W2[t * 400 + i]; }
    if (tid < 200) sW3[tid] = W3[t * 200 + tid];
    if (tid >= 200 && tid < 210) sB3[tid - 200] = b3[t * DD + (tid - 200)];

    // ---- readback statsA (plain loads; kernel boundary is the sync)
    if (tid < NVA) {
        const float* p = redA + (size_t)t * STRA + tid * NS;
        float s = 0.0f;
#pragma unroll
        for (int i = 0; i < NS; ++i) s += p[i];
        sM[tid] = s;
    }
    __syncthreads();

    // ---- BN0 params
    if (tid < 20) {
        float mu  = sM[210 + tid] * INV_B;
        float var = fmaf(-mu, mu, sM[tri(tid, tid)] * INV_B);
        float a   = g0[t * 20 + tid] * rsqrtf(var + EPSV);
        sA0[tid] = a;
        sC0[tid] = fmaf(-mu, a, be0[t * 20 + tid]);
        sMu[tid] = mu;
    }
    __syncthreads();

    // ---- covariance + U = W1 ∘ A0
    for (int i = tid; i < 400; i += NTHR) {
        int k = i / 20, l = i % 20;
        int a = k < l ? k : l, b = k < l ? l : k;
        sCov[i] = fmaf(-sMu[k], sMu[l], sM[tri(a, b)] * INV_B);
        sU[i]   = sW1[i] * sA0[l];
    }
    __syncthreads();

    // ---- P[j,k] = U[j,k] * (Cov[k,:] · U[j,:])
    for (int i = tid; i < 400; i += NTHR) {
        int j = i / 20, k = i % 20;
        float acc = 0.0f;
#pragma unroll
        for (int l = 0; l < 20; ++l)
            acc = fmaf(sCov[k * 20 + l], sU[j * 20 + l], acc);
        sP[i] = acc * sU[i];
    }
    __syncthreads();

    // ---- analytic BN1 params (b1 cancels in BN)
    if (tid < 20) {
        float var1 = 0.0f, m1 = 0.0f;
#pragma unroll
        for (int k = 0; k < 20; ++k) {
            var1 += sP[tid * 20 + k];
            m1    = fmaf(sU[tid * 20 + k], sMu[k], m1);
            m1    = fmaf(sW1[tid * 20 + k], sC0[k], m1);
        }
        float a1 = g1[t * 20 + tid] * rsqrtf(var1 + EPSV);
        sA1[tid] = a1;
        sC1[tid] = fmaf(-m1, a1, be1[t * 20 + tid]);
    }
    __syncthreads();

    // ---- forward layers 1,2 (y2 stays in registers across the barrier)
    float y2[RPT][HH];
#pragma unroll
    for (int r = 0; r < RPT; ++r) {
        float hn[20];
#pragma unroll
        for (int k = 0; k < 10; ++k) hn[k]      = fmaf(xv[r][k], sA0[k],      sC0[k]);
#pragma unroll
        for (int k = 0; k < 10; ++k) hn[10 + k] = fmaf(pv[r][k], sA0[10 + k], sC0[10 + k]);

        float h1[20];
#pragma unroll
        for (int j = 0; j < 20; ++j) {
            float y = 0.0f;
#pragma unroll
            for (int k = 0; k < 20; ++k) y = fmaf(sW1[j * 20 + k], hn[k], y);
            h1[j] = fmaxf(fmaf(y, sA1[j], sC1[j]), 0.0f);
        }
#pragma unroll
        for (int j = 0; j < 20; ++j) {
            float y = 0.0f;
#pragma unroll
            for (int k = 0; k < 20; ++k) y = fmaf(sW2[j * 20 + k], h1[k], y);
            y2[r][j] = y;   // b2 cancels in BN2
        }
    }

    // ---- statsB (combine rows, then reduce)
#pragma unroll
    for (int j = 0; j < 20; ++j) {
        float r = rowsum16(y2[0][j] + y2[1][j]);
        if (lane15) lred[grp * NVA + j] = r;
    }
#pragma unroll
    for (int j = 0; j < 20; ++j) {
        float r = rowsum16(fmaf(y2[0][j], y2[0][j], y2[1][j] * y2[1][j]));
        if (lane15) lred[grp * NVA + 20 + j] = r;
    }
    __syncthreads();
    if (tid < NVB) {
        float acc = 0.0f;
#pragma unroll
        for (int g = 0; g < 16; ++g) acc += lred[g * NVA + tid];
        atomicAdd(redB + (size_t)t * STRB + tid * NS + slot, acc);
    }

    // ================= in-kernel grid barrier =================
    gbar(ctr + (size_t)t * CTRW, tid);

    // ---- BN2 params (relaxed agent atomic readback — no cache inv after spin)
    if (tid < NVB) {
        const float* p = redB + (size_t)t * STRB + tid * NS;
        float s = 0.0f;
#pragma unroll
        for (int i = 0; i < NS; ++i) s += aloadf(p + i);
        sM[tid] = s;
    }
    __syncthreads();
    if (tid < 20) {
        float m   = sM[tid] * INV_B;
        float var = fmaf(-m, m, sM[20 + tid] * INV_B);
        float a   = g2[t * 20 + tid] * rsqrtf(var + EPSV);
        sA2[tid] = a;
        sC2[tid] = fmaf(-m, a, be2[t * 20 + tid]);
    }
    __syncthreads();

    // ---- layer 3 + output + prev
    float ov[RPT][DD];
#pragma unroll
    for (int r = 0; r < RPT; ++r) {
        float h2[20];
#pragma unroll
        for (int j = 0; j < 20; ++j)
            h2[j] = fmaxf(fmaf(y2[r][j], sA2[j], sC2[j]), 0.0f);
#pragma unroll
        for (int d = 0; d < DD; ++d) {
            float a = sB3[d];
#pragma unroll
            for (int j = 0; j < 20; ++j)
                a = fmaf(sW3[d * 20 + j], h2[j], a);
            ov[r][d] = a;
        }
        float2* po = reinterpret_cast<float2*>(outg + (size_t)(gt + r * TT) * TS * DD + t * DD);
#pragma unroll
        for (int i = 0; i < 5; ++i) po[i] = make_float2(ov[r][2 * i], ov[r][2 * i + 1]);
#pragma unroll
        for (int d = 0; d < DD; ++d) prevg[(size_t)d * BATCH + gt + r * TT] = ov[r][d];
    }

    // ---- statsA(t+1): consumer is the next kernel (boundary sync)
    if constexpr (!LAST) {
#define H0A(i) ((i) < DD ? xn[0][i] : ov[0][(i) - DD])
#define H0B(i) ((i) < DD ? xn[1][i] : ov[1][(i) - DD])
        {
            int v = 0;
#pragma unroll
            for (int k = 0; k < 2 * DD; ++k) {
#pragma unroll
                for (int l = k; l < 2 * DD; ++l) {
                    float p = fmaf(H0A(k), H0A(l), H0B(k) * H0B(l));
                    float r = rowsum16(p);
                    if (lane15) lred[grp * NVA + v] = r;
                    ++v;
                }
            }
#pragma unroll
            for (int k = 0; k < 2 * DD; ++k) {
                float r = rowsum16(H0A(k) + H0B(k));
                if (lane15) lred[grp * NVA + 210 + k] = r;
            }
        }
#undef H0A
#undef H0B
        __syncthreads();
        if (tid < NVA) {
            float acc = 0.0f;
#pragma unroll
            for (int g = 0; g < 16; ++g) acc += lred[g * NVA + tid];
            atomicAdd(redA + (size_t)(t + 1) * STRA + tid * NS + slot, acc);
        }
    }
}

extern "C" void kernel_launch(void* const* d_in, const int* in_sizes, int n_in,
                              void* d_out, int out_size, void* d_ws, size_t ws_size,
                              hipStream_t stream) {
    const float* x   = (const float*)d_in[0];
    const float* g0  = (const float*)d_in[1];
    const float* be0 = (const float*)d_in[2];
    const float* W1  = (const float*)d_in[3];
    const float* b1  = (const float*)d_in[4];   (void)b1;  // cancels in BN1
    const float* g1  = (const float*)d_in[5];
    const float* be1 = (const float*)d_in[6];
    const float* W2  = (const float*)d_in[7];
    const float* b2  = (const float*)d_in[8];   (void)b2;  // cancels in BN2
    const float* g2  = (const float*)d_in[9];
    const float* be2 = (const float*)d_in[10];
    const float* W3  = (const float*)d_in[11];
    const float* b3  = (const float*)d_in[12];
    float* out = (float*)d_out;

    const size_t redA_f = (size_t)TS * STRA;    // 55200
    const size_t redB_f = (size_t)TS * STRB;    //  9600
    const size_t ctr_u  = (size_t)TS * CTRW;    //   480
    float*    redA  = (float*)d_ws;
    float*    redB  = redA + redA_f;
    unsigned* ctr   = (unsigned*)(redB + redB_f);
    float*    prevg = (float*)(ctr + ctr_u);    // [DD][BATCH] 5.2 MB (fully written by k_init)

    // zero stat accumulators + barrier counters each replay
    hipMemsetAsync(d_ws, 0, (redA_f + redB_f) * 4 + ctr_u * 4, stream);

    k_init<<<NBLK, NTHR, 0, stream>>>(x, prevg, redA);

    for (int t = 0; t < TS; ++t) {
        if (t + 1 < TS)
            k_step<false><<<NBLK, NTHR, 0, stream>>>(x, prevg, out, W1, W2, W3, b3,
                                                     g0, be0, g1, be1, g2, be2,
                                                     redA, redB, ctr, t);
        else
            k_step<true><<<NBLK, NTHR, 0, stream>>>(x, prevg, out, W1, W2, W3, b3,
                                                    g0, be0, g1, be1, g2, be2,
                                                    redA, redB, ctr, t);
    }
}

// Round 16
// 1337.654 us; speedup vs baseline: 2.4873x; 1.1193x over previous
//
#include <hip/hip_runtime.h>

static constexpr int   BATCH = 131072;
static constexpr int   TS    = 30;
static constexpr int   DD    = 10;
static constexpr int   HH    = 20;
static constexpr float EPSV  = 1e-5f;
static constexpr float INV_B = 1.0f / (float)BATCH;

static constexpr int NBLK = 256;            // == CU count; regular launch, all co-resident
static constexpr int NTHR = 256;
static constexpr int RPT  = 2;
static constexpr int TT   = NBLK * NTHR;    // 65536: rows gt and gt+TT
static constexpr int NS   = 8;              // stat slot spread (blockIdx&7)
static constexpr int GRPS = 8;              // barrier tree groups
static constexpr int GSZ  = NBLK / GRPS;    // 32 arrivals per group counter
static constexpr int NVA  = 230;            // 210 tri second-moments + 20 sums
static constexpr int NVB  = 40;             // 20 sums + 20 sumsq
static constexpr int STRA = NVA * NS;
static constexpr int STRB = NVB * NS;
static constexpr int CTRW = 160;            // uints per step: groups @ g*16, root @ 128

__device__ __forceinline__ int tri(int k, int l) {  // k <= l
    return k * (41 - k) / 2 + (l - k);
}

template <int CTRL>
__device__ __forceinline__ float dpp_add(float v) {
    int x = __builtin_amdgcn_update_dpp(0, __float_as_int(v), CTRL, 0xF, 0xF, true);
    return v + __int_as_float(x);
}

__device__ __forceinline__ float rowsum16(float v) {
    v = dpp_add<0x111>(v);
    v = dpp_add<0x112>(v);
    v = dpp_add<0x114>(v);
    v = dpp_add<0x118>(v);
    return v;   // lane 15 of each 16 holds the total
}

__device__ __forceinline__ float aloadf(const float* p) {
    return __hip_atomic_load(p, __ATOMIC_RELAXED, __HIP_MEMORY_SCOPE_AGENT);
}

// 2-level relaxed tree barrier (R6/R7-proven protocol): 8 group counters
// (64B apart, 32 serialized RMWs each, parallel across L2 slots); last
// arriver of each group bumps the root; all spin on the root. Stats cross
// via device-scope atomicAdd (drained at entry) + relaxed atomic readback,
// so no cache-maintenance fence is needed.
__device__ __forceinline__ void gbar(unsigned* __restrict__ base, int tid, int grp8) {
    __syncthreads();   // drains this block's vmem (incl. stat atomics)
    if (tid == 0) {
        if (__hip_atomic_fetch_add(base + grp8 * 16, 1u, __ATOMIC_RELAXED,
                                   __HIP_MEMORY_SCOPE_AGENT) == (unsigned)(GSZ - 1))
            __hip_atomic_fetch_add(base + 128, 1u, __ATOMIC_RELAXED,
                                   __HIP_MEMORY_SCOPE_AGENT);
        while (__hip_atomic_load(base + 128, __ATOMIC_RELAXED,
                                 __HIP_MEMORY_SCOPE_AGENT) < (unsigned)GRPS)
            __builtin_amdgcn_s_sleep(1);
    }
    __syncthreads();
}

// ---------------- init: prev=0, statsA(0) ----------------
__global__ void __launch_bounds__(NTHR)
k_init(const float* __restrict__ x, float* __restrict__ prevg, float* __restrict__ redA)
{
    __shared__ float lred[16 * NVA];
    const int tid     = threadIdx.x;
    const int grp     = tid >> 4;
    const bool lane15 = (tid & 15) == 15;
    const int gt      = blockIdx.x * NTHR + tid;

    float xv[RPT][DD];
#pragma unroll
    for (int r = 0; r < RPT; ++r) {
        const float2* px = reinterpret_cast<const float2*>(x + (size_t)(gt + r * TT) * TS * DD);
#pragma unroll
        for (int i = 0; i < 5; ++i) { float2 v = px[i]; xv[r][2 * i] = v.x; xv[r][2 * i + 1] = v.y; }
    }
#pragma unroll
    for (int r = 0; r < RPT; ++r)
#pragma unroll
        for (int d = 0; d < DD; ++d) prevg[(size_t)d * BATCH + gt + r * TT] = 0.0f;

#define H0A(i) ((i) < DD ? xv[0][i] : 0.0f)
#define H0B(i) ((i) < DD ? xv[1][i] : 0.0f)
    {
        int v = 0;
#pragma unroll
        for (int k = 0; k < 2 * DD; ++k) {
#pragma unroll
            for (int l = k; l < 2 * DD; ++l) {
                float p = fmaf(H0A(k), H0A(l), H0B(k) * H0B(l));
                float r = rowsum16(p);
                if (lane15) lred[grp * NVA + v] = r;
                ++v;
            }
        }
#pragma unroll
        for (int k = 0; k < 2 * DD; ++k) {
            float r = rowsum16(H0A(k) + H0B(k));
            if (lane15) lred[grp * NVA + 210 + k] = r;
        }
    }
#undef H0A
#undef H0B
    __syncthreads();
    if (tid < NVA) {
        float acc = 0.0f;
#pragma unroll
        for (int g = 0; g < 16; ++g) acc += lred[g * NVA + tid];
        atomicAdd(redA + tid * NS + (blockIdx.x & (NS - 1)), acc);
    }
}

// ---------------- one full step, single kernel, one in-kernel tree barrier
template <bool LAST>
__global__ void __launch_bounds__(NTHR)
k_step(const float* __restrict__ x, float* __restrict__ prevg, float* __restrict__ outg,
       const float* __restrict__ W1, const float* __restrict__ W2,
       const float* __restrict__ W3, const float* __restrict__ b3,
       const float* __restrict__ g0, const float* __restrict__ be0,
       const float* __restrict__ g1, const float* __restrict__ be1,
       const float* __restrict__ g2, const float* __restrict__ be2,
       float* __restrict__ redA, float* __restrict__ redB,
       unsigned* __restrict__ ctr, int t)
{
    __shared__ float lred[16 * NVA];
    __shared__ float sM[230], sMu[20], sCov[400], sU[400], sP[400];
    __shared__ float sW1[400], sW2[400], sW3[200], sB3[10];
    __shared__ float sA0[20], sC0[20], sA1[20], sC1[20], sA2[20], sC2[20];

    const int tid     = threadIdx.x;
    const int grp     = tid >> 4;
    const bool lane15 = (tid & 15) == 15;
    const int slot    = blockIdx.x & (NS - 1);
    const int grp8    = blockIdx.x & (GRPS - 1);
    const int gt      = blockIdx.x * NTHR + tid;

    // ---- hoisted per-row loads (latency overlaps the param preamble)
    float xv[RPT][DD], pv[RPT][DD], xn[RPT][DD];
#pragma unroll
    for (int r = 0; r < RPT; ++r) {
        const float2* px = reinterpret_cast<const float2*>(x + (size_t)(gt + r * TT) * TS * DD + t * DD);
#pragma unroll
        for (int i = 0; i < 5; ++i) { float2 v = px[i]; xv[r][2 * i] = v.x; xv[r][2 * i + 1] = v.y; }
    }
#pragma unroll
    for (int r = 0; r < RPT; ++r)
#pragma unroll
        for (int d = 0; d < DD; ++d) pv[r][d] = prevg[(size_t)d * BATCH + gt + r * TT];
    if constexpr (!LAST) {
#pragma unroll
        for (int r = 0; r < RPT; ++r) {
            const float2* px = reinterpret_cast<const float2*>(x + (size_t)(gt + r * TT) * TS * DD + (t + 1) * DD);
#pragma unroll
            for (int i = 0; i < 5; ++i) { float2 v = px[i]; xn[r][2 * i] = v.x; xn[r][2 * i + 1] = v.y; }
        }
    }

    // ---- stage weights
    for (int i = tid; i < 400; i += NTHR) { sW1[i] = W1[t * 400 + i]; sW2[i] = W2[t * 400 + i]; }
    if (tid < 200) sW3[tid] = W3[t * 200 + tid];
    if (tid >= 200 && tid < 210) sB3[tid - 200] = b3[t * DD + (tid - 200)];

    // ---- readback statsA (plain loads; kernel boundary is the sync)
    if (tid < NVA) {
        const float* p = redA + (size_t)t * STRA + tid * NS;
        float s = 0.0f;
#pragma unroll
        for (int i = 0; i < NS; ++i) s += p[i];
        sM[tid] = s;
    }
    __syncthreads();

    // ---- BN0 params
    if (tid < 20) {
        float mu  = sM[210 + tid] * INV_B;
        float var = fmaf(-mu, mu, sM[tri(tid, tid)] * INV_B);
        float a   = g0[t * 20 + tid] * rsqrtf(var + EPSV);
        sA0[tid] = a;
        sC0[tid] = fmaf(-mu, a, be0[t * 20 + tid]);
        sMu[tid] = mu;
    }
    __syncthreads();

    // ---- covariance + U = W1 ∘ A0
    for (int i = tid; i < 400; i += NTHR) {
        int k = i / 20, l = i % 20;
        int a = k < l ? k : l, b = k < l ? l : k;
        sCov[i] = fmaf(-sMu[k], sMu[l], sM[tri(a, b)] * INV_B);
        sU[i]   = sW1[i] * sA0[l];
    }
    __syncthreads();

    // ---- P[j,k] = U[j,k] * (Cov[k,:] · U[j,:])
    for (int i = tid; i < 400; i += NTHR) {
        int j = i / 20, k = i % 20;
        float acc = 0.0f;
#pragma unroll
        for (int l = 0; l < 20; ++l)
            acc = fmaf(sCov[k * 20 + l], sU[j * 20 + l], acc);
        sP[i] = acc * sU[i];
    }
    __syncthreads();

    // ---- analytic BN1 params (b1 cancels in BN)
    if (tid < 20) {
        float var1 = 0.0f, m1 = 0.0f;
#pragma unroll
        for (int k = 0; k < 20; ++k) {
            var1 += sP[tid * 20 + k];
            m1    = fmaf(sU[tid * 20 + k], sMu[k], m1);
            m1    = fmaf(sW1[tid * 20 + k], sC0[k], m1);
        }
        float a1 = g1[t * 20 + tid] * rsqrtf(var1 + EPSV);
        sA1[tid] = a1;
        sC1[tid] = fmaf(-m1, a1, be1[t * 20 + tid]);
    }
    __syncthreads();

    // ---- forward layers 1,2 (y2 stays in registers across the barrier)
    float y2[RPT][HH];
#pragma unroll
    for (int r = 0; r < RPT; ++r) {
        float hn[20];
#pragma unroll
        for (int k = 0; k < 10; ++k) hn[k]      = fmaf(xv[r][k], sA0[k],      sC0[k]);
#pragma unroll
        for (int k = 0; k < 10; ++k) hn[10 + k] = fmaf(pv[r][k], sA0[10 + k], sC0[10 + k]);

        float h1[20];
#pragma unroll
        for (int j = 0; j < 20; ++j) {
            float y = 0.0f;
#pragma unroll
            for (int k = 0; k < 20; ++k) y = fmaf(sW1[j * 20 + k], hn[k], y);
            h1[j] = fmaxf(fmaf(y, sA1[j], sC1[j]), 0.0f);
        }
#pragma unroll
        for (int j = 0; j < 20; ++j) {
            float y = 0.0f;
#pragma unroll
            for (int k = 0; k < 20; ++k) y = fmaf(sW2[j * 20 + k], h1[k], y);
            y2[r][j] = y;   // b2 cancels in BN2
        }
    }

    // ---- statsB (combine rows, then reduce)
#pragma unroll
    for (int j = 0; j < 20; ++j) {
        float r = rowsum16(y2[0][j] + y2[1][j]);
        if (lane15) lred[grp * NVA + j] = r;
    }
#pragma unroll
    for (int j = 0; j < 20; ++j) {
        float r = rowsum16(fmaf(y2[0][j], y2[0][j], y2[1][j] * y2[1][j]));
        if (lane15) lred[grp * NVA + 20 + j] = r;
    }
    __syncthreads();
    if (tid < NVB) {
        float acc = 0.0f;
#pragma unroll
        for (int g = 0; g < 16; ++g) acc += lred[g * NVA + tid];
        atomicAdd(redB + (size_t)t * STRB + tid * NS + slot, acc);
    }

    // ================= in-kernel tree barrier =================
    gbar(ctr + (size_t)t * CTRW, tid, grp8);

    // ---- BN2 params (relaxed agent atomic readback)
    if (tid < NVB) {
        const float* p = redB + (size_t)t * STRB + tid * NS;
        float s = 0.0f;
#pragma unroll
        for (int i = 0; i < NS; ++i) s += aloadf(p + i);
        sM[tid] = s;
    }
    __syncthreads();
    if (tid < 20) {
        float m   = sM[tid] * INV_B;
        float var = fmaf(-m, m, sM[20 + tid] * INV_B);
        float a   = g2[t * 20 + tid] * rsqrtf(var + EPSV);
        sA2[tid] = a;
        sC2[tid] = fmaf(-m, a, be2[t * 20 + tid]);
    }
    __syncthreads();

    // ---- layer 3 + output + prev
    float ov[RPT][DD];
#pragma unroll
    for (int r = 0; r < RPT; ++r) {
        float h2[20];
#pragma unroll
        for (int j = 0; j < 20; ++j)
            h2[j] = fmaxf(fmaf(y2[r][j], sA2[j], sC2[j]), 0.0f);
#pragma unroll
        for (int d = 0; d < DD; ++d) {
            float a = sB3[d];
#pragma unroll
            for (int j = 0; j < 20; ++j)
                a = fmaf(sW3[d * 20 + j], h2[j], a);
            ov[r][d] = a;
        }
        float2* po = reinterpret_cast<float2*>(outg + (size_t)(gt + r * TT) * TS * DD + t * DD);
#pragma unroll
        for (int i = 0; i < 5; ++i) po[i] = make_float2(ov[r][2 * i], ov[r][2 * i + 1]);
#pragma unroll
        for (int d = 0; d < DD; ++d) prevg[(size_t)d * BATCH + gt + r * TT] = ov[r][d];
    }

    // ---- statsA(t+1): consumer is the next kernel (boundary sync)
    if constexpr (!LAST) {
#define H0A(i) ((i) < DD ? xn[0][i] : ov[0][(i) - DD])
#define H0B(i) ((i) < DD ? xn[1][i] : ov[1][(i) - DD])
        {
            int v = 0;
#pragma unroll
            for (int k = 0; k < 2 * DD; ++k) {
#pragma unroll
                for (int l = k; l < 2 * DD; ++l) {
                    float p = fmaf(H0A(k), H0A(l), H0B(k) * H0B(l));
                    float r = rowsum16(p);
                    if (lane15) lred[grp * NVA + v] = r;
                    ++v;
                }
            }
#pragma unroll
            for (int k = 0; k < 2 * DD; ++k) {
                float r = rowsum16(H0A(k) + H0B(k));
                if (lane15) lred[grp * NVA + 210 + k] = r;
            }
        }
#undef H0A
#undef H0B
        __syncthreads();
        if (tid < NVA) {
            float acc = 0.0f;
#pragma unroll
            for (int g = 0; g < 16; ++g) acc += lred[g * NVA + tid];
            atomicAdd(redA + (size_t)(t + 1) * STRA + tid * NS + slot, acc);
        }
    }
}

extern "C" void kernel_launch(void* const* d_in, const int* in_sizes, int n_in,
                              void* d_out, int out_size, void* d_ws, size_t ws_size,
                              hipStream_t stream) {
    const float* x   = (const float*)d_in[0];
    const float* g0  = (const float*)d_in[1];
    const float* be0 = (const float*)d_in[2];
    const float* W1  = (const float*)d_in[3];
    const float* b1  = (const float*)d_in[4];   (void)b1;  // cancels in BN1
    const float* g1  = (const float*)d_in[5];
    const float* be1 = (const float*)d_in[6];
    const float* W2  = (const float*)d_in[7];
    const float* b2  = (const float*)d_in[8];   (void)b2;  // cancels in BN2
    const float* g2  = (const float*)d_in[9];
    const float* be2 = (const float*)d_in[10];
    const float* W3  = (const float*)d_in[11];
    const float* b3  = (const float*)d_in[12];
    float* out = (float*)d_out;

    const size_t redA_f = (size_t)TS * STRA;    // 55200
    const size_t redB_f = (size_t)TS * STRB;    //  9600
    const size_t ctr_u  = (size_t)TS * CTRW;    //  4800
    float*    redA  = (float*)d_ws;
    float*    redB  = redA + redA_f;
    unsigned* ctr   = (unsigned*)(redB + redB_f);
    float*    prevg = (float*)(ctr + ctr_u);    // [DD][BATCH] 5.2 MB (fully written by k_init)

    // zero stat accumulators + barrier counters each replay
    hipMemsetAsync(d_ws, 0, (redA_f + redB_f) * 4 + ctr_u * 4, stream);

    k_init<<<NBLK, NTHR, 0, stream>>>(x, prevg, redA);

    for (int t = 0; t < TS; ++t) {
        if (t + 1 < TS)
            k_step<false><<<NBLK, NTHR, 0, stream>>>(x, prevg, out, W1, W2, W3, b3,
                                                     g0, be0, g1, be1, g2, be2,
                                                     redA, redB, ctr, t);
        else
            k_step<true><<<NBLK, NTHR, 0, stream>>>(x, prevg, out, W1, W2, W3, b3,
                                                    g0, be0, g1, be1, g2, be2,
                                                    redA, redB, ctr, t);
    }
}

// Round 17
// 1299.320 us; speedup vs baseline: 2.5607x; 1.0295x over previous
//
#include <hip/hip_runtime.h>

static constexpr int   BATCH = 131072;
static constexpr int   TS    = 30;
static constexpr int   DD    = 10;
static constexpr int   HH    = 20;
static constexpr float EPSV  = 1e-5f;
static constexpr float INV_B = 1.0f / (float)BATCH;

static constexpr int NBLK = 256;            // == CU count; REGULAR launch (coop failed R8/R12)
static constexpr int NTHR = 256;
static constexpr int RPT  = 2;
static constexpr int TT   = NBLK * NTHR;    // 65536: rows gt and gt+TT
static constexpr int NS   = 8;              // stat slot spread (blockIdx&7)
static constexpr int GRPS = 8;              // barrier tree groups
static constexpr int GSZ  = NBLK / GRPS;    // 32 arrivals per group counter
static constexpr int NVA  = 230;            // 210 tri second-moments + 20 sums
static constexpr int NVB  = 40;             // 20 sums + 20 sumsq
static constexpr int STRA = NVA * NS;
static constexpr int STRB = NVB * NS;
static constexpr int CTRW = 160;            // uints per phase: groups @ g*16, root @128
static constexpr int NPH  = 2 * TS + 1;     // 61 phase slots (60 barriers used)

__device__ __forceinline__ int tri(int k, int l) {  // k <= l
    return k * (41 - k) / 2 + (l - k);
}

template <int CTRL>
__device__ __forceinline__ float dpp_add(float v) {
    int x = __builtin_amdgcn_update_dpp(0, __float_as_int(v), CTRL, 0xF, 0xF, true);
    return v + __int_as_float(x);
}

__device__ __forceinline__ float rowsum16(float v) {
    v = dpp_add<0x111>(v);
    v = dpp_add<0x112>(v);
    v = dpp_add<0x114>(v);
    v = dpp_add<0x118>(v);
    return v;   // lane 15 of each 16 holds the total
}

__device__ __forceinline__ float aloadf(const float* p) {
    return __hip_atomic_load(p, __ATOMIC_RELAXED, __HIP_MEMORY_SCOPE_AGENT);
}

// 2-level relaxed tree barrier (R15/R16-proven at regular launch).
__device__ __forceinline__ void gbar(unsigned* __restrict__ base, int tid, int grp8) {
    __syncthreads();   // drains this block's vmem (incl. stat atomics)
    if (tid == 0) {
        if (__hip_atomic_fetch_add(base + grp8 * 16, 1u, __ATOMIC_RELAXED,
                                   __HIP_MEMORY_SCOPE_AGENT) == (unsigned)(GSZ - 1))
            __hip_atomic_fetch_add(base + 128, 1u, __ATOMIC_RELAXED,
                                   __HIP_MEMORY_SCOPE_AGENT);
        while (__hip_atomic_load(base + 128, __ATOMIC_RELAXED,
                                 __HIP_MEMORY_SCOPE_AGENT) < (unsigned)GRPS)
            __builtin_amdgcn_s_sleep(1);
    }
    __syncthreads();
}

// ---------------- the whole sequence in ONE regular-launch persistent kernel
__global__ void __launch_bounds__(NTHR)
rnn_all(const float* __restrict__ x, float* __restrict__ outg,
        const float* __restrict__ W1, const float* __restrict__ W2,
        const float* __restrict__ W3, const float* __restrict__ b3,
        const float* __restrict__ g0, const float* __restrict__ be0,
        const float* __restrict__ g1, const float* __restrict__ be1,
        const float* __restrict__ g2, const float* __restrict__ be2,
        float* __restrict__ redA, float* __restrict__ redB,
        unsigned* __restrict__ ctr)
{
    __shared__ float lred[16 * NVA];
    __shared__ float sM[230], sMu[20], sCov[400], sU[400], sP[400];
    __shared__ float sW1[400], sW2[400], sW3[200], sB3[10];
    __shared__ float sA0[20], sC0[20], sA1[20], sC1[20], sA2[20], sC2[20];

    const int tid     = threadIdx.x;
    const int grp     = tid >> 4;
    const bool lane15 = (tid & 15) == 15;
    const int slot    = blockIdx.x & (NS - 1);
    const int grp8    = blockIdx.x & (GRPS - 1);
    const int gt      = blockIdx.x * NTHR + tid;

    // prev lives in REGISTERS for the whole sequence
    float pv[RPT][DD];
#pragma unroll
    for (int r = 0; r < RPT; ++r)
#pragma unroll
        for (int d = 0; d < DD; ++d) pv[r][d] = 0.0f;

    float xv[RPT][DD];
#pragma unroll
    for (int r = 0; r < RPT; ++r) {
        const float2* px = reinterpret_cast<const float2*>(x + (size_t)(gt + r * TT) * TS * DD);
#pragma unroll
        for (int i = 0; i < 5; ++i) { float2 v = px[i]; xv[r][2 * i] = v.x; xv[r][2 * i + 1] = v.y; }
    }

    // ---- statsA(0): prev==0, so only x-moments are nonzero
#define H0A(i) ((i) < DD ? xv[0][i] : 0.0f)
#define H0B(i) ((i) < DD ? xv[1][i] : 0.0f)
    {
        int v = 0;
#pragma unroll
        for (int k = 0; k < 2 * DD; ++k) {
#pragma unroll
            for (int l = k; l < 2 * DD; ++l) {
                float p = fmaf(H0A(k), H0A(l), H0B(k) * H0B(l));
                float r = rowsum16(p);
                if (lane15) lred[grp * NVA + v] = r;
                ++v;
            }
        }
#pragma unroll
        for (int k = 0; k < 2 * DD; ++k) {
            float r = rowsum16(H0A(k) + H0B(k));
            if (lane15) lred[grp * NVA + 210 + k] = r;
        }
    }
#undef H0A
#undef H0B
    __syncthreads();
    if (tid < NVA) {
        float acc = 0.0f;
#pragma unroll
        for (int g = 0; g < 16; ++g) acc += lred[g * NVA + tid];
        atomicAdd(redA + tid * NS + slot, acc);
    }
    gbar(ctr + (size_t)(2 * TS) * CTRW, tid, grp8);   // init barrier (slot 60)

    for (int t = 0; t < TS; ++t) {
        // ---- stage weights for this step
        for (int i = tid; i < 400; i += NTHR) { sW1[i] = W1[t * 400 + i]; sW2[i] = W2[t * 400 + i]; }
        if (tid < 200) sW3[tid] = W3[t * 200 + tid];
        if (tid >= 200 && tid < 210) sB3[tid - 200] = b3[t * DD + (tid - 200)];

        // ---- prefetch x(t+1)
        float xn[RPT][DD];
        if (t + 1 < TS) {
#pragma unroll
            for (int r = 0; r < RPT; ++r) {
                const float2* px = reinterpret_cast<const float2*>(x + (size_t)(gt + r * TT) * TS * DD + (t + 1) * DD);
#pragma unroll
                for (int i = 0; i < 5; ++i) { float2 v = px[i]; xn[r][2 * i] = v.x; xn[r][2 * i + 1] = v.y; }
            }
        }

        // ---- readback statsA[t] (relaxed agent atomic loads)
        if (tid < NVA) {
            const float* p = redA + (size_t)t * STRA + tid * NS;
            float s = 0.0f;
#pragma unroll
            for (int i = 0; i < NS; ++i) s += aloadf(p + i);
            sM[tid] = s;
        }
        __syncthreads();

        // ---- BN0 params
        if (tid < 20) {
            float mu  = sM[210 + tid] * INV_B;
            float var = fmaf(-mu, mu, sM[tri(tid, tid)] * INV_B);
            float a   = g0[t * 20 + tid] * rsqrtf(var + EPSV);
            sA0[tid] = a;
            sC0[tid] = fmaf(-mu, a, be0[t * 20 + tid]);
            sMu[tid] = mu;
        }
        __syncthreads();

        // ---- covariance + U = W1 ∘ A0
        for (int i = tid; i < 400; i += NTHR) {
            int k = i / 20, l = i % 20;
            int a = k < l ? k : l, b = k < l ? l : k;
            sCov[i] = fmaf(-sMu[k], sMu[l], sM[tri(a, b)] * INV_B);
            sU[i]   = sW1[i] * sA0[l];
        }
        __syncthreads();

        // ---- P[j,k] = U[j,k] * (Cov[k,:] · U[j,:])
        for (int i = tid; i < 400; i += NTHR) {
            int j = i / 20, k = i % 20;
            float acc = 0.0f;
#pragma unroll
            for (int l = 0; l < 20; ++l)
                acc = fmaf(sCov[k * 20 + l], sU[j * 20 + l], acc);
            sP[i] = acc * sU[i];
        }
        __syncthreads();

        // ---- analytic BN1 params (b1 cancels in BN)
        if (tid < 20) {
            float var1 = 0.0f, m1 = 0.0f;
#pragma unroll
            for (int k = 0; k < 20; ++k) {
                var1 += sP[tid * 20 + k];
                m1    = fmaf(sU[tid * 20 + k], sMu[k], m1);
                m1    = fmaf(sW1[tid * 20 + k], sC0[k], m1);
            }
            float a1 = g1[t * 20 + tid] * rsqrtf(var1 + EPSV);
            sA1[tid] = a1;
            sC1[tid] = fmaf(-m1, a1, be1[t * 20 + tid]);
        }
        __syncthreads();

        // ---- forward layers 1,2 (y2 stays in registers)
        float y2[RPT][HH];
#pragma unroll
        for (int r = 0; r < RPT; ++r) {
            float hn[20];
#pragma unroll
            for (int k = 0; k < 10; ++k) hn[k]      = fmaf(xv[r][k], sA0[k],      sC0[k]);
#pragma unroll
            for (int k = 0; k < 10; ++k) hn[10 + k] = fmaf(pv[r][k], sA0[10 + k], sC0[10 + k]);

            float h1[20];
#pragma unroll
            for (int j = 0; j < 20; ++j) {
                float y = 0.0f;
#pragma unroll
                for (int k = 0; k < 20; ++k) y = fmaf(sW1[j * 20 + k], hn[k], y);
                h1[j] = fmaxf(fmaf(y, sA1[j], sC1[j]), 0.0f);
            }
#pragma unroll
            for (int j = 0; j < 20; ++j) {
                float y = 0.0f;
#pragma unroll
                for (int k = 0; k < 20; ++k) y = fmaf(sW2[j * 20 + k], h1[k], y);
                y2[r][j] = y;   // b2 cancels in BN2
            }
        }

        // ---- statsB (combine rows, then reduce)
#pragma unroll
        for (int j = 0; j < 20; ++j) {
            float r = rowsum16(y2[0][j] + y2[1][j]);
            if (lane15) lred[grp * NVA + j] = r;
        }
#pragma unroll
        for (int j = 0; j < 20; ++j) {
            float r = rowsum16(fmaf(y2[0][j], y2[0][j], y2[1][j] * y2[1][j]));
            if (lane15) lred[grp * NVA + 20 + j] = r;
        }
        __syncthreads();
        if (tid < NVB) {
            float acc = 0.0f;
#pragma unroll
            for (int g = 0; g < 16; ++g) acc += lred[g * NVA + tid];
            atomicAdd(redB + (size_t)t * STRB + tid * NS + slot, acc);
        }

        // ================= barrier 1 (statsB ready) =================
        gbar(ctr + (size_t)(2 * t) * CTRW, tid, grp8);

        // ---- BN2 params (relaxed agent atomic readback)
        if (tid < NVB) {
            const float* p = redB + (size_t)t * STRB + tid * NS;
            float s = 0.0f;
#pragma unroll
            for (int i = 0; i < NS; ++i) s += aloadf(p + i);
            sM[tid] = s;
        }
        __syncthreads();
        if (tid < 20) {
            float m   = sM[tid] * INV_B;
            float var = fmaf(-m, m, sM[20 + tid] * INV_B);
            float a   = g2[t * 20 + tid] * rsqrtf(var + EPSV);
            sA2[tid] = a;
            sC2[tid] = fmaf(-m, a, be2[t * 20 + tid]);
        }
        __syncthreads();

        // ---- layer 3 + output + prev (registers)
        float ov[RPT][DD];
#pragma unroll
        for (int r = 0; r < RPT; ++r) {
            float h2[20];
#pragma unroll
            for (int j = 0; j < 20; ++j)
                h2[j] = fmaxf(fmaf(y2[r][j], sA2[j], sC2[j]), 0.0f);
#pragma unroll
            for (int d = 0; d < DD; ++d) {
                float a = sB3[d];
#pragma unroll
                for (int j = 0; j < 20; ++j)
                    a = fmaf(sW3[d * 20 + j], h2[j], a);
                ov[r][d] = a;
            }
            float2* po = reinterpret_cast<float2*>(outg + (size_t)(gt + r * TT) * TS * DD + t * DD);
#pragma unroll
            for (int i = 0; i < 5; ++i) po[i] = make_float2(ov[r][2 * i], ov[r][2 * i + 1]);
#pragma unroll
            for (int d = 0; d < DD; ++d) pv[r][d] = ov[r][d];
        }

        // ---- statsA(t+1) + barrier 2
        if (t + 1 < TS) {
#define H0A(i) ((i) < DD ? xn[0][i] : ov[0][(i) - DD])
#define H0B(i) ((i) < DD ? xn[1][i] : ov[1][(i) - DD])
            {
                int v = 0;
#pragma unroll
                for (int k = 0; k < 2 * DD; ++k) {
#pragma unroll
                    for (int l = k; l < 2 * DD; ++l) {
                        float p = fmaf(H0A(k), H0A(l), H0B(k) * H0B(l));
                        float r = rowsum16(p);
                        if (lane15) lred[grp * NVA + v] = r;
                        ++v;
                    }
                }
#pragma unroll
                for (int k = 0; k < 2 * DD; ++k) {
                    float r = rowsum16(H0A(k) + H0B(k));
                    if (lane15) lred[grp * NVA + 210 + k] = r;
                }
            }
#undef H0A
#undef H0B
            __syncthreads();
            if (tid < NVA) {
                float acc = 0.0f;
#pragma unroll
                for (int g = 0; g < 16; ++g) acc += lred[g * NVA + tid];
                atomicAdd(redA + (size_t)(t + 1) * STRA + tid * NS + slot, acc);
            }
            gbar(ctr + (size_t)(2 * t + 1) * CTRW, tid, grp8);

#pragma unroll
            for (int r = 0; r < RPT; ++r)
#pragma unroll
                for (int d = 0; d < DD; ++d) xv[r][d] = xn[r][d];
        }
    }
}

extern "C" void kernel_launch(void* const* d_in, const int* in_sizes, int n_in,
                              void* d_out, int out_size, void* d_ws, size_t ws_size,
                              hipStream_t stream) {
    const float* x   = (const float*)d_in[0];
    const float* g0  = (const float*)d_in[1];
    const float* be0 = (const float*)d_in[2];
    const float* W1  = (const float*)d_in[3];
    const float* b1  = (const float*)d_in[4];   (void)b1;  // cancels in BN1
    const float* g1  = (const float*)d_in[5];
    const float* be1 = (const float*)d_in[6];
    const float* W2  = (const float*)d_in[7];
    const float* b2  = (const float*)d_in[8];   (void)b2;  // cancels in BN2
    const float* g2  = (const float*)d_in[9];
    const float* be2 = (const float*)d_in[10];
    const float* W3  = (const float*)d_in[11];
    const float* b3  = (const float*)d_in[12];
    float* out = (float*)d_out;

    const size_t redA_f = (size_t)TS * STRA;    // 55200
    const size_t redB_f = (size_t)TS * STRB;    //  9600
    const size_t ctr_u  = (size_t)NPH * CTRW;   //  9760
    float*    redA  = (float*)d_ws;
    float*    redB  = redA + redA_f;
    unsigned* ctr   = (unsigned*)(redB + redB_f);

    // zero stat accumulators + barrier counters each replay
    hipMemsetAsync(d_ws, 0, (redA_f + redB_f) * 4 + ctr_u * 4, stream);

    rnn_all<<<NBLK, NTHR, 0, stream>>>(x, out, W1, W2, W3, b3,
                                       g0, be0, g1, be1, g2, be2,
                                       redA, redB, ctr);
}